// Round 1
// baseline (205.067 us; speedup 1.0000x reference)
//
#include <hip/hip_runtime.h>
#include <math.h>

#define NPT 2048
#define KNN 20
#define KT_STRIDE 2052   // 16B-aligned rows (8208B), quad writes 2-way (free)

typedef const float* fp;
typedef __attribute__((ext_vector_type(4))) float f32x4;
typedef __attribute__((ext_vector_type(8))) short s16x8;

// round-to-nearest-even f32 -> bf16 bits (inputs are finite)
__device__ __forceinline__ ushort f2bf_rne(float v) {
    unsigned u = __float_as_uint(v);
    unsigned r = u + 0x7FFFu + ((u >> 16) & 1u);
    return (ushort)(r >> 16);
}
__device__ __forceinline__ float bfbits2f(ushort h) {
    return __uint_as_float(((unsigned)h) << 16);
}
__device__ __forceinline__ s16x8 ldfrag(const ushort* p) {
    union { uint4 u; s16x8 s; } cv;
    cv.u = *reinterpret_cast<const uint4*>(p);
    return cv.s;
}
// 8 consecutive f32 -> bf16 hi/lo fragment pair (in-register fragify)
__device__ __forceinline__ void f8_hilo(const float* row, s16x8* hi, s16x8* lo) {
    float4 f0 = *reinterpret_cast<const float4*>(row);
    float4 f1 = *reinterpret_cast<const float4*>(row + 4);
    float f[8] = {f0.x, f0.y, f0.z, f0.w, f1.x, f1.y, f1.z, f1.w};
    union { ushort u[8]; s16x8 s; } H, L;
    #pragma unroll
    for (int j = 0; j < 8; j++) {
        ushort h = f2bf_rne(f[j]);
        H.u[j] = h;
        L.u[j] = f2bf_rne(f[j] - bfbits2f(h));
    }
    *hi = H.s; *lo = L.s;
}

// ---------------------------------------------------------------------------
// prep_all: blocks [0,256) = fragify x + xx; blocks [256,835) = weight frags
//   (q/k/v K=128; wc=[w1x | w1a@wm] K=256 on-the-fly; w2 K=256), b1p, stats=0.
// ---------------------------------------------------------------------------
__global__ __launch_bounds__(256) void prep_all(
    fp xbf, fp wq, fp wk, fp wv, fp wm, fp w1, fp w2, fp bm, fp b1,
    float* xx, ushort* xhiF, ushort* xloF,
    ushort* wqFhi, ushort* wqFlo, ushort* wkFhi, ushort* wkFlo,
    ushort* wvFhi, ushort* wvFlo,
    ushort* wcFhi, ushort* wcFlo, ushort* w2Fhi, ushort* w2Flo,
    float* b1p, float* stats) {
    int t = threadIdx.x;
    if (blockIdx.x < 256) {                 // ---- x frags + xx ----
        __shared__ float xs[16][129];
        __shared__ float xpart[16][17];
        int p0 = blockIdx.x * 16;
        int b = p0 >> 11, n0 = p0 & 2047;
        fp xb = xbf + (size_t)b * 128 * NPT;
        {
            int c = t >> 1, half = t & 1;
            float4 f0 = *reinterpret_cast<const float4*>(xb + (size_t)c * NPT + n0 + half * 8);
            float4 f1 = *reinterpret_cast<const float4*>(xb + (size_t)c * NPT + n0 + half * 8 + 4);
            xs[half * 8 + 0][c] = f0.x; xs[half * 8 + 1][c] = f0.y;
            xs[half * 8 + 2][c] = f0.z; xs[half * 8 + 3][c] = f0.w;
            xs[half * 8 + 4][c] = f1.x; xs[half * 8 + 5][c] = f1.y;
            xs[half * 8 + 6][c] = f1.z; xs[half * 8 + 7][c] = f1.w;
        }
        __syncthreads();
        int p = t & 15, g = t >> 4, c0 = g * 8;
        float f[8];
        #pragma unroll
        for (int j = 0; j < 8; j++) f[j] = xs[p][c0 + j];
        float ps = 0.f;
        #pragma unroll
        for (int j = 0; j < 8; j++) ps += f[j] * f[j];
        xpart[p][g] = ps;
        union { ushort u[8]; uint4 q; } H, L;
        #pragma unroll
        for (int j = 0; j < 8; j++) {
            ushort hi = f2bf_rne(f[j]);
            H.u[j] = hi;
            L.u[j] = f2bf_rne(f[j] - bfbits2f(hi));
        }
        size_t off = ((size_t)blockIdx.x * 4 + (c0 >> 5)) * 512
                   + (size_t)(((((c0 >> 3) & 3) * 16) + p) * 8);
        *reinterpret_cast<uint4*>(xhiF + off) = H.q;
        *reinterpret_cast<uint4*>(xloF + off) = L.q;
        __syncthreads();
        if (t < 16) {
            float s = 0.f;
            #pragma unroll
            for (int gg = 0; gg < 16; gg++) s += xpart[t][gg];
            xx[p0 + t] = s;
        }
        return;
    }
    int wid = (blockIdx.x - 256) * 256 + t;
    if (wid < 49152) {                      // q/k/v frags (K=128)
        int which = wid >> 14, e = wid & 16383;
        int lane = (e >> 3) & 63, j = e & 7, kk = (e >> 9) & 3, nt = e >> 11;
        int n = nt * 16 + (lane & 15);
        int k = kk * 32 + (lane >> 4) * 8 + j;
        fp src = which == 0 ? wq : which == 1 ? wk : wv;
        float v = src[n * 128 + k];
        ushort hi = f2bf_rne(v);
        (which == 0 ? wqFhi : which == 1 ? wkFhi : wvFhi)[e] = hi;
        (which == 0 ? wqFlo : which == 1 ? wkFlo : wvFlo)[e] = f2bf_rne(v - bfbits2f(hi));
    } else if (wid < 114688) {              // wc frags (N=256, K=256)
        int e = wid - 49152;
        int j = e & 7, lane = (e >> 3) & 63, kk = (e >> 9) & 7, nt = e >> 12;
        int n = nt * 16 + (lane & 15);
        int k = kk * 32 + (lane >> 4) * 8 + j;
        float v;
        if (k < 128) {
            v = w1[n * 256 + k];
        } else {                            // W[n][k-128] = w1a@wm on the fly
            int c = k - 128;
            float s = 0.f;
            for (int i = 0; i < 128; i += 4) {
                float4 wr = *reinterpret_cast<const float4*>(w1 + n * 256 + 128 + i);
                s += wr.x * wm[(i + 0) * 128 + c];
                s += wr.y * wm[(i + 1) * 128 + c];
                s += wr.z * wm[(i + 2) * 128 + c];
                s += wr.w * wm[(i + 3) * 128 + c];
            }
            v = s;
        }
        ushort hi = f2bf_rne(v);
        wcFhi[e] = hi;
        wcFlo[e] = f2bf_rne(v - bfbits2f(hi));
    } else if (wid < 147456) {              // w2 frags (N=128, K=256)
        int e = wid - 114688;
        int j = e & 7, lane = (e >> 3) & 63, kk = (e >> 9) & 7, nt = e >> 12;
        int n = nt * 16 + (lane & 15);
        int k = kk * 32 + (lane >> 4) * 8 + j;
        float v = w2[n * 256 + k];
        ushort hi = f2bf_rne(v);
        w2Fhi[e] = hi;
        w2Flo[e] = f2bf_rne(v - bfbits2f(hi));
    } else if (wid < 147712) {              // b1p = b1 + w1a@bm
        int o = wid - 147456;
        float s = b1[o];
        for (int i = 0; i < 128; i++)
            s += w1[o * 256 + 128 + i] * bm[i];
        b1p[o] = s;
    } else {                                // BN stats zero (512)
        stats[wid - 147712] = 0.0f;
    }
}

// ---------------------------------------------------------------------------
// gemm_key_topk: ONE block per 16-point row-tile (256 blocks, 512 threads).
//   Phase 1: qkv GEMM for the tile (reuses A-frags; 3 (mat,nt) pairs/wave).
//   Phase 2: key GEMM 16 rows x 2048 cols into LDS (16 ct tiles/wave, 2-wide
//            ILP), value = 2*dot - xx[col] (xx[row] const per row: ordering-
//            preserving, matches previous materialized-key bits exactly).
//   Phase 3: per-row top-20 with EXACT threshold prefilter, straight from
//            LDS (2 rows/wave). Eliminates key0/key1 (32MB write + 32MB read)
//            and the separate k2b_all launch.
// ---------------------------------------------------------------------------
#define MERGE(off) { float ov = __shfl_xor(bv, off); int oi = __shfl_xor(bi, off); \
                     if (ov > bv || (ov == bv && oi < bi)) { bv = ov; bi = oi; } }

__global__ __launch_bounds__(512) void gemm_key_topk(
    const ushort* xhiF, const ushort* xloF, const float* xx,
    const ushort* wqFhi, const ushort* wqFlo,
    const ushort* wkFhi, const ushort* wkFlo,
    const ushort* wvFhi, const ushort* wvFlo,
    fp bq, fp bk, fp bv_, float* qT, float* kT, float* vT,
    int* idxbuf) {
    __shared__ float key_s[16 * KT_STRIDE];     // 131,328 B
    __shared__ float sv[8][256];                //   8,192 B
    __shared__ int   si[8][256];                //   8,192 B
    int tt = threadIdx.x, w = tt >> 6, lane = tt & 63;
    int rt = blockIdx.x;                        // global row-tile 0..255
    int slab = rt >> 7, rtl = rt & 127;
    int cl = lane & 15, quad = lane >> 4;

    // ---- A-frags for this row-tile (shared by qkv + key phases) ----
    s16x8 ahi[4], alo[4];
    #pragma unroll
    for (int kk = 0; kk < 4; kk++) {
        ahi[kk] = ldfrag(xhiF + ((size_t)(rt * 4 + kk)) * 512 + lane * 8);
        alo[kk] = ldfrag(xloF + ((size_t)(rt * 4 + kk)) * 512 + lane * 8);
    }

    // ---- Phase 1: qkv (24 (mat,nt) pairs, 3 per wave) ----
    {
        f32x4 acc[3];
        #pragma unroll
        for (int i = 0; i < 3; i++) acc[i] = (f32x4){0.f, 0.f, 0.f, 0.f};
        int base = w * 3;
        #pragma unroll
        for (int kk = 0; kk < 4; kk++) {
            #pragma unroll
            for (int i = 0; i < 3; i++) {
                int pair = base + i;
                int mat = pair >> 3, nt = pair & 7;
                const ushort* whi = mat == 0 ? wqFhi : mat == 1 ? wkFhi : wvFhi;
                const ushort* wlo = mat == 0 ? wqFlo : mat == 1 ? wkFlo : wvFlo;
                s16x8 bhi = ldfrag(whi + ((size_t)(nt * 4 + kk)) * 512 + lane * 8);
                s16x8 blo = ldfrag(wlo + ((size_t)(nt * 4 + kk)) * 512 + lane * 8);
                acc[i] = __builtin_amdgcn_mfma_f32_16x16x32_bf16(ahi[kk], bhi, acc[i], 0, 0, 0);
                acc[i] = __builtin_amdgcn_mfma_f32_16x16x32_bf16(alo[kk], bhi, acc[i], 0, 0, 0);
                acc[i] = __builtin_amdgcn_mfma_f32_16x16x32_bf16(ahi[kk], blo, acc[i], 0, 0, 0);
            }
        }
        int p0 = rt * 16;
        #pragma unroll
        for (int i = 0; i < 3; i++) {
            int pair = base + i;
            int mat = pair >> 3, nt = pair & 7;
            fp bias    = mat == 0 ? bq : mat == 1 ? bk : bv_;
            float* out = mat == 0 ? qT : mat == 1 ? kT : vT;
            int o = nt * 16 + cl;
            float bvv = bias[o];
            #pragma unroll
            for (int r = 0; r < 4; r++)
                out[(size_t)(p0 + quad * 4 + r) * 128 + o] = acc[i][r] + bvv;
        }
    }

    // ---- Phase 2: key GEMM into LDS (wave w: col-tiles w*16 .. w*16+15) ----
    for (int c = 0; c < 16; c += 2) {
        int ctl0 = w * 16 + c, ctl1 = ctl0 + 1;
        int ct0 = slab * 128 + ctl0, ct1 = ct0 + 1;
        f32x4 a0 = (f32x4){0.f, 0.f, 0.f, 0.f};
        f32x4 a1 = (f32x4){0.f, 0.f, 0.f, 0.f};
        #pragma unroll
        for (int kk = 0; kk < 4; kk++) {
            s16x8 b0h = ldfrag(xhiF + ((size_t)(ct0 * 4 + kk)) * 512 + lane * 8);
            s16x8 b1h = ldfrag(xhiF + ((size_t)(ct1 * 4 + kk)) * 512 + lane * 8);
            s16x8 b0l = ldfrag(xloF + ((size_t)(ct0 * 4 + kk)) * 512 + lane * 8);
            s16x8 b1l = ldfrag(xloF + ((size_t)(ct1 * 4 + kk)) * 512 + lane * 8);
            a0 = __builtin_amdgcn_mfma_f32_16x16x32_bf16(ahi[kk], b0h, a0, 0, 0, 0);
            a1 = __builtin_amdgcn_mfma_f32_16x16x32_bf16(ahi[kk], b1h, a1, 0, 0, 0);
            a0 = __builtin_amdgcn_mfma_f32_16x16x32_bf16(alo[kk], b0h, a0, 0, 0, 0);
            a1 = __builtin_amdgcn_mfma_f32_16x16x32_bf16(alo[kk], b1h, a1, 0, 0, 0);
            a0 = __builtin_amdgcn_mfma_f32_16x16x32_bf16(ahi[kk], b0l, a0, 0, 0, 0);
            a1 = __builtin_amdgcn_mfma_f32_16x16x32_bf16(ahi[kk], b1l, a1, 0, 0, 0);
        }
        float xx0 = xx[slab * 2048 + ctl0 * 16 + cl];
        float xx1 = xx[slab * 2048 + ctl1 * 16 + cl];
        #pragma unroll
        for (int r = 0; r < 4; r++) {
            key_s[(quad * 4 + r) * KT_STRIDE + ctl0 * 16 + cl] = 2.0f * a0[r] - xx0;
            key_s[(quad * 4 + r) * KT_STRIDE + ctl1 * 16 + cl] = 2.0f * a1[r] - xx1;
        }
    }
    __syncthreads();

    // ---- Phase 3: top-20 per row, 2 rows per wave, straight from LDS ----
    for (int rr = 0; rr < 2; rr++) {
        int local = w * 2 + rr;
        int rowl = rtl * 16 + local;            // row within slab
        const float* rowp = key_s + local * KT_STRIDE;
        float rv[32];
        #pragma unroll
        for (int j = 0; j < 8; j++) {
            float4 v = *reinterpret_cast<const float4*>(rowp + j * 256 + lane * 4);
            rv[j * 4 + 0] = v.x; rv[j * 4 + 1] = v.y;
            rv[j * 4 + 2] = v.z; rv[j * 4 + 3] = v.w;
        }
        // --- lane max (value only) ---
        float lm = rv[0];
        #pragma unroll
        for (int sl = 1; sl < 32; sl++) lm = fmaxf(lm, rv[sl]);
        // --- bitonic sort of lane maxima (ascending across 64 lanes) ---
        float bs = lm;
        #pragma unroll
        for (int k = 2; k <= 64; k <<= 1) {
            #pragma unroll
            for (int j = k >> 1; j > 0; j >>= 1) {
                float o = __shfl_xor(bs, j);
                bool dirDesc = (lane & k) != 0;
                bool upper   = (lane & j) != 0;
                bs = (upper != dirDesc) ? fmaxf(bs, o) : fminf(bs, o);
            }
        }
        float T = __shfl(bs, 44);               // 20th largest lane-max
        // --- survivor count + wave prefix sum ---
        int cnt = 0;
        #pragma unroll
        for (int sl = 0; sl < 32; sl++) cnt += (rv[sl] >= T) ? 1 : 0;
        int inc = cnt;
        #pragma unroll
        for (int off = 1; off < 64; off <<= 1) {
            int o = __shfl_up(inc, off);
            if (lane >= off) inc += o;
        }
        int S = __shfl(inc, 63);
        int pos = inc - cnt;
        bool small = (S <= 256);
        if (small) {                            // compact survivors to LDS
            #pragma unroll
            for (int sl = 0; sl < 32; sl++) {
                if (rv[sl] >= T) {
                    sv[w][pos] = rv[sl];
                    si[w][pos] = (sl >> 2) * 256 + lane * 4 + (sl & 3);
                    pos++;
                }
            }
        }
        if (small) {
            float vl[4]; int il[4];
            #pragma unroll
            for (int s = 0; s < 4; s++) {
                int g = lane + s * 64;
                bool ok = g < S;
                vl[s] = ok ? sv[w][g] : -3.4e38f;
                il[s] = ok ? si[w][g] : 0x7FFFFFFF;
            }
            unsigned removed = 0u;
            for (int iter = 0; iter < KNN; iter++) {
                float bv = -3.4e38f; int bi = 0x7FFFFFFF;
                #pragma unroll
                for (int s = 0; s < 4; s++) {
                    bool live = ((removed >> s) & 1u) == 0u;
                    if (live && (vl[s] > bv || (vl[s] == bv && il[s] < bi))) {
                        bv = vl[s]; bi = il[s];
                    }
                }
                MERGE(32) MERGE(16) MERGE(8) MERGE(4) MERGE(2) MERGE(1)
                if (lane == 0) idxbuf[(size_t)(slab * 2048 + rowl) * KNN + iter] = bi & 2047;
                #pragma unroll
                for (int s = 0; s < 4; s++)     // indices unique: safe removal
                    if (il[s] == bi) removed |= 1u << s;
            }
        } else {                                // exact fallback: full 32-slot scan
            unsigned removed = 0u;
            for (int iter = 0; iter < KNN; iter++) {
                float bv = -3.4e38f; int bi = 0;
                #pragma unroll
                for (int sl = 0; sl < 32; sl++) {
                    bool live = ((removed >> sl) & 1u) == 0u;
                    if (live && rv[sl] > bv) { bv = rv[sl]; bi = (sl >> 2) * 256 + lane * 4 + (sl & 3); }
                }
                MERGE(32) MERGE(16) MERGE(8) MERGE(4) MERGE(2) MERGE(1)
                bi &= 2047;
                if (lane == 0) idxbuf[(size_t)(slab * 2048 + rowl) * KNN + iter] = bi;
                if (((bi >> 2) & 63) == lane) removed |= 1u << ((bi >> 8) * 4 + (bi & 3));
            }
        }
    }
}

// ---------------------------------------------------------------------------
// k3: sparse mutual-KNN attention, 2 points/block; inline mutuality scan.
// ---------------------------------------------------------------------------
__global__ __launch_bounds__(256) void k3_attn(
    fp qT, fp kT, fp vT, const int* idxbuf, float* avT) {
    __shared__ float sbuf[2][KNN * 4];
    __shared__ int   mlist[2][KNN];
    __shared__ int   cnt_s[2];
    int tt = threadIdx.x;
    int half = tt >> 7, t = tt & 127;
    int p = blockIdx.x * 2 + half;
    int b = p >> 11, n = p & 2047;
    int bbase = b * NPT;
    int h = t >> 5;

    if ((tt >> 6) == half * 2) {
        int lane = tt & 63;
        bool fl = false; int m = 0;
        if (lane < KNN) {
            m = idxbuf[(size_t)p * KNN + lane] & 2047;
            const int4* mrow = reinterpret_cast<const int4*>(idxbuf + (size_t)(bbase + m) * KNN);
            int4 r0 = mrow[0], r1 = mrow[1], r2 = mrow[2], r3 = mrow[3], r4 = mrow[4];
            fl = (r0.x == n) || (r0.y == n) || (r0.z == n) || (r0.w == n)
              || (r1.x == n) || (r1.y == n) || (r1.z == n) || (r1.w == n)
              || (r2.x == n) || (r2.y == n) || (r2.z == n) || (r2.w == n)
              || (r3.x == n) || (r3.y == n) || (r3.z == n) || (r3.w == n)
              || (r4.x == n) || (r4.y == n) || (r4.z == n) || (r4.w == n);
        }
        unsigned long long mask = __ballot(fl);
        int pos = __popcll(mask & ((1ull << lane) - 1ull));
        if (fl) mlist[half][pos] = m;
        if (lane == 0) cnt_s[half] = (int)__popcll(mask);
    }
    __syncthreads();

    int cnt = cnt_s[half];
    float qv = qT[(size_t)p * 128 + t];
    for (int jj = 0; jj < cnt; jj++) {
        int m = mlist[half][jj];
        float prod = qv * kT[(size_t)(bbase + m) * 128 + t];
        prod += __shfl_xor(prod, 16);
        prod += __shfl_xor(prod, 8);
        prod += __shfl_xor(prod, 4);
        prod += __shfl_xor(prod, 2);
        prod += __shfl_xor(prod, 1);
        if ((t & 31) == 0) sbuf[half][jj * 4 + h] = prod * 0.17677669529663687f;
    }
    __syncthreads();

    float mx = -3.4e38f;
    for (int j = 0; j < cnt; j++) mx = fmaxf(mx, sbuf[half][j * 4 + h]);
    float den = 0.f;
    for (int j = 0; j < cnt; j++) den += expf(sbuf[half][j * 4 + h] - mx);
    float inv = (cnt > 0) ? (1.0f / den) : 0.0f;
    float acc = 0.f;
    for (int j = 0; j < cnt; j++) {
        float pw = expf(sbuf[half][j * 4 + h] - mx) * inv;
        acc += pw * vT[(size_t)(bbase + mlist[half][j]) * 128 + t];
    }
    avT[(size_t)p * 128 + t] = acc;
}

// ---------------------------------------------------------------------------
// k4b: h = w1x@x + W@av + b1p via MFMA (K=256); epilogue: hbuf + BN stats.
// ---------------------------------------------------------------------------
__global__ __launch_bounds__(256) void k4b_h(
    const ushort* xhiF, const ushort* xloF, const float* avT,
    const ushort* wcFhi, const ushort* wcFlo,
    const float* b1p, float* hbuf, float* stats) {
    int t = threadIdx.x, cs = t >> 6, lane = t & 63;
    int rt = blockIdx.x;                    // 0..255
    int p0 = rt * 16;

    f32x4 acc[4];
    #pragma unroll
    for (int j = 0; j < 4; j++) acc[j] = (f32x4){0.f, 0.f, 0.f, 0.f};

    for (int kk = 0; kk < 8; kk++) {
        s16x8 ahi, alo;
        if (kk < 4) {
            ahi = ldfrag(xhiF + ((size_t)(rt * 4 + kk)) * 512 + lane * 8);
            alo = ldfrag(xloF + ((size_t)(rt * 4 + kk)) * 512 + lane * 8);
        } else {
            const float* arow = avT + (size_t)(p0 + (lane & 15)) * 128
                              + (kk - 4) * 32 + (lane >> 4) * 8;
            f8_hilo(arow, &ahi, &alo);
        }
        #pragma unroll
        for (int j = 0; j < 4; j++) {
            int nt = cs * 4 + j;
            s16x8 bhi = ldfrag(wcFhi + ((size_t)(nt * 8 + kk)) * 512 + lane * 8);
            s16x8 blo = ldfrag(wcFlo + ((size_t)(nt * 8 + kk)) * 512 + lane * 8);
            acc[j] = __builtin_amdgcn_mfma_f32_16x16x32_bf16(ahi, bhi, acc[j], 0, 0, 0);
            acc[j] = __builtin_amdgcn_mfma_f32_16x16x32_bf16(alo, bhi, acc[j], 0, 0, 0);
            acc[j] = __builtin_amdgcn_mfma_f32_16x16x32_bf16(ahi, blo, acc[j], 0, 0, 0);
        }
    }

    int cl = lane & 15, quad = lane >> 4;
    #pragma unroll
    for (int j = 0; j < 4; j++) {
        int o = cs * 64 + j * 16 + cl;
        float bb = b1p[o];
        float s = 0.f, s2 = 0.f;
        #pragma unroll
        for (int r = 0; r < 4; r++) {
            float v = acc[j][r] + bb;
            hbuf[(size_t)(p0 + quad * 4 + r) * 256 + o] = v;
            s += v; s2 += v * v;
        }
        s  += __shfl_xor(s, 16);  s  += __shfl_xor(s, 32);
        s2 += __shfl_xor(s2, 16); s2 += __shfl_xor(s2, 32);
        if (quad == 0) {
            atomicAdd(&stats[o], s);
            atomicAdd(&stats[256 + o], s2);
        }
    }
}

// ---------------------------------------------------------------------------
// k5b: out = w2@relu(BN(h)) + b2 + x via MFMA (K=256), BN in-register.
// ---------------------------------------------------------------------------
__global__ __launch_bounds__(256) void k5b_out(
    const float* hbuf, const float* stats, fp gamma, fp beta,
    const ushort* w2Fhi, const ushort* w2Flo,
    fp b2, fp xbf, float* out) {
    int t = threadIdx.x, wvi = t >> 6, lane = t & 63;
    int rt = blockIdx.x;                    // 0..255
    int p0 = rt * 16;

    f32x4 acc[2];
    acc[0] = (f32x4){0.f, 0.f, 0.f, 0.f};
    acc[1] = (f32x4){0.f, 0.f, 0.f, 0.f};

    for (int kk = 0; kk < 8; kk++) {
        int c0 = kk * 32 + (lane >> 4) * 8;
        const float* hrow = hbuf + (size_t)(p0 + (lane & 15)) * 256 + c0;
        float4 f0 = *reinterpret_cast<const float4*>(hrow);
        float4 f1 = *reinterpret_cast<const float4*>(hrow + 4);
        float4 s0 = *reinterpret_cast<const float4*>(stats + c0);
        float4 s1 = *reinterpret_cast<const float4*>(stats + c0 + 4);
        float4 q0 = *reinterpret_cast<const float4*>(stats + 256 + c0);
        float4 q1 = *reinterpret_cast<const float4*>(stats + 256 + c0 + 4);
        float4 g0 = *reinterpret_cast<const float4*>(gamma + c0);
        float4 g1 = *reinterpret_cast<const float4*>(gamma + c0 + 4);
        float4 e0 = *reinterpret_cast<const float4*>(beta + c0);
        float4 e1 = *reinterpret_cast<const float4*>(beta + c0 + 4);
        float f[8] = {f0.x, f0.y, f0.z, f0.w, f1.x, f1.y, f1.z, f1.w};
        float sm[8] = {s0.x, s0.y, s0.z, s0.w, s1.x, s1.y, s1.z, s1.w};
        float sq[8] = {q0.x, q0.y, q0.z, q0.w, q1.x, q1.y, q1.z, q1.w};
        float gm[8] = {g0.x, g0.y, g0.z, g0.w, g1.x, g1.y, g1.z, g1.w};
        float bt[8] = {e0.x, e0.y, e0.z, e0.w, e1.x, e1.y, e1.z, e1.w};
        union { ushort u[8]; s16x8 s; } H, L;
        #pragma unroll
        for (int j = 0; j < 8; j++) {
            float mu  = sm[j] * (1.0f / 4096.0f);
            float var = fmaxf(sq[j] * (1.0f / 4096.0f) - mu * mu, 0.0f);
            float a    = gm[j] / sqrtf(var + 1e-5f);
            float cadd = bt[j] - mu * a;
            float v = fmaxf(f[j] * a + cadd, 0.0f);
            ushort hi = f2bf_rne(v);
            H.u[j] = hi;
            L.u[j] = f2bf_rne(v - bfbits2f(hi));
        }
        s16x8 ahi = H.s, alo = L.s;
        #pragma unroll
        for (int jj = 0; jj < 2; jj++) {
            int nt = wvi * 2 + jj;
            s16x8 bhi = ldfrag(w2Fhi + ((size_t)(nt * 8 + kk)) * 512 + lane * 8);
            s16x8 blo = ldfrag(w2Flo + ((size_t)(nt * 8 + kk)) * 512 + lane * 8);
            acc[jj] = __builtin_amdgcn_mfma_f32_16x16x32_bf16(ahi, bhi, acc[jj], 0, 0, 0);
            acc[jj] = __builtin_amdgcn_mfma_f32_16x16x32_bf16(alo, bhi, acc[jj], 0, 0, 0);
            acc[jj] = __builtin_amdgcn_mfma_f32_16x16x32_bf16(ahi, blo, acc[jj], 0, 0, 0);
        }
    }
    int cl = lane & 15, quad = lane >> 4;
    int b = p0 >> 11, n0 = p0 & 2047;
    #pragma unroll
    for (int jj = 0; jj < 2; jj++) {
        int o = (wvi * 2 + jj) * 16 + cl;
        float bb = b2[o];
        size_t base = (size_t)b * 128 * NPT + (size_t)o * NPT + n0 + quad * 4;
        float4 xv = *reinterpret_cast<const float4*>(xbf + base);
        float4 ov;
        ov.x = acc[jj][0] + bb + xv.x;
        ov.y = acc[jj][1] + bb + xv.y;
        ov.z = acc[jj][2] + bb + xv.z;
        ov.w = acc[jj][3] + bb + xv.w;
        *reinterpret_cast<float4*>(out + base) = ov;
    }
}

// ---------------------------------------------------------------------------
// Workspace layout (11,423,744 B; key0/key1 eliminated by fused kernel):
//   0        qT 2MB [fused->k3]  <- hbuf 4MB (k4b->k5b) aliases qT+kT
//   2097152  kT 2MB | 4194304 vT 2MB | 6291456 avT 2MB [k3->k4b]
//   8388608  xx 16KB | 8404992 idxb 320KB | 8732672 stats 2KB | 8734720 b1p 2KB
//   8736768  wq/wk/wv frags 6x32KB
//   8933376  wcFhi/lo 2x128KB | 9195520 w2Fhi/lo 2x64KB
//   9326592  xhiF 1MB | 10375168 xloF 1MB
// ---------------------------------------------------------------------------
#define WS_FULL 11423744u

extern "C" void kernel_launch(void* const* d_in, const int* in_sizes, int n_in,
                              void* d_out, int out_size, void* d_ws, size_t ws_size,
                              hipStream_t stream) {
    fp desc1 = (fp)d_in[0];
    fp wq = (fp)d_in[1];  fp bq = (fp)d_in[2];
    fp wk = (fp)d_in[3];  fp bk = (fp)d_in[4];
    fp wv = (fp)d_in[5];  fp bv = (fp)d_in[6];
    fp wm = (fp)d_in[7];  fp bm = (fp)d_in[8];
    fp w1 = (fp)d_in[9];  fp b1 = (fp)d_in[10];
    fp gamma = (fp)d_in[11]; fp beta = (fp)d_in[12];
    fp w2 = (fp)d_in[13]; fp b2 = (fp)d_in[14];

    if (ws_size < (size_t)WS_FULL) return;  // all-zero out => ws too small

    char* ws = (char*)d_ws;
    float*  qT    = (float*) (ws + 0);
    float*  kT    = (float*) (ws + 2097152);
    float*  vT    = (float*) (ws + 4194304);
    float*  avT   = (float*) (ws + 6291456);
    float*  xx    = (float*) (ws + 8388608);
    int*    idxb  = (int*)   (ws + 8404992);
    float*  stats = (float*) (ws + 8732672);
    float*  b1p   = (float*) (ws + 8734720);
    ushort* wqFhi = (ushort*)(ws + 8736768);
    ushort* wqFlo = (ushort*)(ws + 8769536);
    ushort* wkFhi = (ushort*)(ws + 8802304);
    ushort* wkFlo = (ushort*)(ws + 8835072);
    ushort* wvFhi = (ushort*)(ws + 8867840);
    ushort* wvFlo = (ushort*)(ws + 8900608);
    ushort* wcFhi = (ushort*)(ws + 8933376);
    ushort* wcFlo = (ushort*)(ws + 9064448);
    ushort* w2Fhi = (ushort*)(ws + 9195520);
    ushort* w2Flo = (ushort*)(ws + 9261056);
    ushort* xhiF  = (ushort*)(ws + 9326592);
    ushort* xloF  = (ushort*)(ws + 10375168);
    float*  hbuf  = (float*) (ws + 0);      // aliases qT+kT (dead after k3)

    prep_all<<<835, 256, 0, stream>>>(desc1, wq, wk, wv, wm, w1, w2, bm, b1,
                                      xx, xhiF, xloF,
                                      wqFhi, wqFlo, wkFhi, wkFlo, wvFhi, wvFlo,
                                      wcFhi, wcFlo, w2Fhi, w2Flo, b1p, stats);
    gemm_key_topk<<<256, 512, 0, stream>>>(xhiF, xloF, xx,
                                           wqFhi, wqFlo, wkFhi, wkFlo,
                                           wvFhi, wvFlo,
                                           bq, bk, bv, qT, kT, vT, idxb);
    k3_attn<<<2048, 256, 0, stream>>>(qT, kT, vT, idxb, avT);
    k4b_h<<<256, 256, 0, stream>>>(xhiF, xloF, avT, wcFhi, wcFlo,
                                   b1p, hbuf, stats);
    k5b_out<<<256, 256, 0, stream>>>(hbuf, stats, gamma, beta, w2Fhi, w2Flo,
                                     b2, desc1, (float*)d_out);
}

// Round 2
// 187.025 us; speedup vs baseline: 1.0965x; 1.0965x over previous
//
#include <hip/hip_runtime.h>
#include <math.h>

#define NPT 2048
#define KNN 20

typedef const float* fp;
typedef __attribute__((ext_vector_type(4))) float f32x4;
typedef __attribute__((ext_vector_type(8))) short s16x8;

// round-to-nearest-even f32 -> bf16 bits (inputs are finite)
__device__ __forceinline__ ushort f2bf_rne(float v) {
    unsigned u = __float_as_uint(v);
    unsigned r = u + 0x7FFFu + ((u >> 16) & 1u);
    return (ushort)(r >> 16);
}
__device__ __forceinline__ float bfbits2f(ushort h) {
    return __uint_as_float(((unsigned)h) << 16);
}
__device__ __forceinline__ s16x8 ldfrag(const ushort* p) {
    union { uint4 u; s16x8 s; } cv;
    cv.u = *reinterpret_cast<const uint4*>(p);
    return cv.s;
}
// 8 consecutive f32 -> bf16 hi/lo fragment pair (in-register fragify)
__device__ __forceinline__ void f8_hilo(const float* row, s16x8* hi, s16x8* lo) {
    float4 f0 = *reinterpret_cast<const float4*>(row);
    float4 f1 = *reinterpret_cast<const float4*>(row + 4);
    float f[8] = {f0.x, f0.y, f0.z, f0.w, f1.x, f1.y, f1.z, f1.w};
    union { ushort u[8]; s16x8 s; } H, L;
    #pragma unroll
    for (int j = 0; j < 8; j++) {
        ushort h = f2bf_rne(f[j]);
        H.u[j] = h;
        L.u[j] = f2bf_rne(f[j] - bfbits2f(h));
    }
    *hi = H.s; *lo = L.s;
}

// ---------------------------------------------------------------------------
// prep_all: blocks [0,256) = fragify x + xx; blocks [256,835) = weight frags
//   (q/k/v K=128; wc=[w1x | w1a@wm] K=256 on-the-fly; w2 K=256), b1p, stats=0.
// ---------------------------------------------------------------------------
__global__ __launch_bounds__(256) void prep_all(
    fp xbf, fp wq, fp wk, fp wv, fp wm, fp w1, fp w2, fp bm, fp b1,
    float* xx, ushort* xhiF, ushort* xloF,
    ushort* wqFhi, ushort* wqFlo, ushort* wkFhi, ushort* wkFlo,
    ushort* wvFhi, ushort* wvFlo,
    ushort* wcFhi, ushort* wcFlo, ushort* w2Fhi, ushort* w2Flo,
    float* b1p, float* stats) {
    int t = threadIdx.x;
    if (blockIdx.x < 256) {                 // ---- x frags + xx ----
        __shared__ float xs[16][129];
        __shared__ float xpart[16][17];
        int p0 = blockIdx.x * 16;
        int b = p0 >> 11, n0 = p0 & 2047;
        fp xb = xbf + (size_t)b * 128 * NPT;
        {
            int c = t >> 1, half = t & 1;
            float4 f0 = *reinterpret_cast<const float4*>(xb + (size_t)c * NPT + n0 + half * 8);
            float4 f1 = *reinterpret_cast<const float4*>(xb + (size_t)c * NPT + n0 + half * 8 + 4);
            xs[half * 8 + 0][c] = f0.x; xs[half * 8 + 1][c] = f0.y;
            xs[half * 8 + 2][c] = f0.z; xs[half * 8 + 3][c] = f0.w;
            xs[half * 8 + 4][c] = f1.x; xs[half * 8 + 5][c] = f1.y;
            xs[half * 8 + 6][c] = f1.z; xs[half * 8 + 7][c] = f1.w;
        }
        __syncthreads();
        int p = t & 15, g = t >> 4, c0 = g * 8;
        float f[8];
        #pragma unroll
        for (int j = 0; j < 8; j++) f[j] = xs[p][c0 + j];
        float ps = 0.f;
        #pragma unroll
        for (int j = 0; j < 8; j++) ps += f[j] * f[j];
        xpart[p][g] = ps;
        union { ushort u[8]; uint4 q; } H, L;
        #pragma unroll
        for (int j = 0; j < 8; j++) {
            ushort hi = f2bf_rne(f[j]);
            H.u[j] = hi;
            L.u[j] = f2bf_rne(f[j] - bfbits2f(hi));
        }
        size_t off = ((size_t)blockIdx.x * 4 + (c0 >> 5)) * 512
                   + (size_t)(((((c0 >> 3) & 3) * 16) + p) * 8);
        *reinterpret_cast<uint4*>(xhiF + off) = H.q;
        *reinterpret_cast<uint4*>(xloF + off) = L.q;
        __syncthreads();
        if (t < 16) {
            float s = 0.f;
            #pragma unroll
            for (int gg = 0; gg < 16; gg++) s += xpart[t][gg];
            xx[p0 + t] = s;
        }
        return;
    }
    int wid = (blockIdx.x - 256) * 256 + t;
    if (wid < 49152) {                      // q/k/v frags (K=128)
        int which = wid >> 14, e = wid & 16383;
        int lane = (e >> 3) & 63, j = e & 7, kk = (e >> 9) & 3, nt = e >> 11;
        int n = nt * 16 + (lane & 15);
        int k = kk * 32 + (lane >> 4) * 8 + j;
        fp src = which == 0 ? wq : which == 1 ? wk : wv;
        float v = src[n * 128 + k];
        ushort hi = f2bf_rne(v);
        (which == 0 ? wqFhi : which == 1 ? wkFhi : wvFhi)[e] = hi;
        (which == 0 ? wqFlo : which == 1 ? wkFlo : wvFlo)[e] = f2bf_rne(v - bfbits2f(hi));
    } else if (wid < 114688) {              // wc frags (N=256, K=256)
        int e = wid - 49152;
        int j = e & 7, lane = (e >> 3) & 63, kk = (e >> 9) & 7, nt = e >> 12;
        int n = nt * 16 + (lane & 15);
        int k = kk * 32 + (lane >> 4) * 8 + j;
        float v;
        if (k < 128) {
            v = w1[n * 256 + k];
        } else {                            // W[n][k-128] = w1a@wm on the fly
            int c = k - 128;
            float s = 0.f;
            for (int i = 0; i < 128; i += 4) {
                float4 wr = *reinterpret_cast<const float4*>(w1 + n * 256 + 128 + i);
                s += wr.x * wm[(i + 0) * 128 + c];
                s += wr.y * wm[(i + 1) * 128 + c];
                s += wr.z * wm[(i + 2) * 128 + c];
                s += wr.w * wm[(i + 3) * 128 + c];
            }
            v = s;
        }
        ushort hi = f2bf_rne(v);
        wcFhi[e] = hi;
        wcFlo[e] = f2bf_rne(v - bfbits2f(hi));
    } else if (wid < 147456) {              // w2 frags (N=128, K=256)
        int e = wid - 114688;
        int j = e & 7, lane = (e >> 3) & 63, kk = (e >> 9) & 7, nt = e >> 12;
        int n = nt * 16 + (lane & 15);
        int k = kk * 32 + (lane >> 4) * 8 + j;
        float v = w2[n * 256 + k];
        ushort hi = f2bf_rne(v);
        w2Fhi[e] = hi;
        w2Flo[e] = f2bf_rne(v - bfbits2f(hi));
    } else if (wid < 147712) {              // b1p = b1 + w1a@bm
        int o = wid - 147456;
        float s = b1[o];
        for (int i = 0; i < 128; i++)
            s += w1[o * 256 + 128 + i] * bm[i];
        b1p[o] = s;
    } else {                                // BN stats zero (512)
        stats[wid - 147712] = 0.0f;
    }
}

// ---------------------------------------------------------------------------
// gemm_key_topk v2: 256 blocks x 1024 threads (16 waves), 16 rows/block.
//   Key block (16 x 2048) lives entirely in REGISTERS: wave w owns cols
//   [w*128, w*128+128), 8 independent MFMA chains (f32x4 key[8] = 32 VGPR).
//   Top-20: per-row 64 chunk-maxima (chunks of 32 cols) -> bitonic-64
//   threshold (exact lower bound on the 20th largest) -> LDS survivor
//   compaction (atomics, ~24/row) -> exact selection. Bit-identical values
//   and selection vs the materialized-key version. Overflow (>256 survivors)
//   falls back to a register dump into global scratch + full scan (exact).
// ---------------------------------------------------------------------------
#define MERGE(off) { float ov = __shfl_xor(bv, off); int oi = __shfl_xor(bi, off); \
                     if (ov > bv || (ov == bv && oi < bi)) { bv = ov; bi = oi; } }

__global__ __launch_bounds__(1024) void gemm_key_topk(
    const ushort* xhiF, const ushort* xloF, const float* xx,
    const ushort* wqFhi, const ushort* wqFlo,
    const ushort* wkFhi, const ushort* wkFlo,
    const ushort* wvFhi, const ushort* wvFlo,
    fp bq, fp bk, fp bv_, float* qT, float* kT, float* vT,
    int* idxbuf, float* scratch) {
    __shared__ float chm[16][64];           // 4 KB  per-row chunk maxima
    __shared__ float sv[16][256];           // 16 KB survivor values
    __shared__ int   si[16][256];           // 16 KB survivor cols
    __shared__ float Trow[16];
    __shared__ int   rowcnt[16];
    __shared__ int   ovfAll;
    int tt = threadIdx.x, w = tt >> 6, lane = tt & 63;
    int rt = blockIdx.x;                    // global row-tile 0..255
    int slab = rt >> 7, rtl = rt & 127;
    int cl = lane & 15, quad = lane >> 4;

    if (tt < 16) rowcnt[tt] = 0;
    if (tt == 16) ovfAll = 0;

    // ---- A-frags for this row-tile (shared by qkv + key phases) ----
    s16x8 ahi[4], alo[4];
    #pragma unroll
    for (int kk = 0; kk < 4; kk++) {
        ahi[kk] = ldfrag(xhiF + ((size_t)(rt * 4 + kk)) * 512 + lane * 8);
        alo[kk] = ldfrag(xloF + ((size_t)(rt * 4 + kk)) * 512 + lane * 8);
    }

    // ---- Phase 1: qkv (24 (mat,nt) pairs; waves 0..11 take 2 each) ----
    if (w < 12) {
        f32x4 acc[2];
        acc[0] = (f32x4){0.f, 0.f, 0.f, 0.f};
        acc[1] = (f32x4){0.f, 0.f, 0.f, 0.f};
        #pragma unroll
        for (int kk = 0; kk < 4; kk++) {
            #pragma unroll
            for (int i = 0; i < 2; i++) {
                int pair = w * 2 + i;
                int mat = pair >> 3, nt = pair & 7;
                const ushort* whi = mat == 0 ? wqFhi : mat == 1 ? wkFhi : wvFhi;
                const ushort* wlo = mat == 0 ? wqFlo : mat == 1 ? wkFlo : wvFlo;
                s16x8 bhi = ldfrag(whi + ((size_t)(nt * 4 + kk)) * 512 + lane * 8);
                s16x8 blo = ldfrag(wlo + ((size_t)(nt * 4 + kk)) * 512 + lane * 8);
                acc[i] = __builtin_amdgcn_mfma_f32_16x16x32_bf16(ahi[kk], bhi, acc[i], 0, 0, 0);
                acc[i] = __builtin_amdgcn_mfma_f32_16x16x32_bf16(alo[kk], bhi, acc[i], 0, 0, 0);
                acc[i] = __builtin_amdgcn_mfma_f32_16x16x32_bf16(ahi[kk], blo, acc[i], 0, 0, 0);
            }
        }
        int p0 = rt * 16;
        #pragma unroll
        for (int i = 0; i < 2; i++) {
            int pair = w * 2 + i;
            int mat = pair >> 3, nt = pair & 7;
            fp bias    = mat == 0 ? bq : mat == 1 ? bk : bv_;
            float* out = mat == 0 ? qT : mat == 1 ? kT : vT;
            int o = nt * 16 + cl;
            float bvv = bias[o];
            #pragma unroll
            for (int r = 0; r < 4; r++)
                out[(size_t)(p0 + quad * 4 + r) * 128 + o] = acc[i][r] + bvv;
        }
    }

    // ---- Phase 2: key GEMM into registers (wave w: cols w*128..w*128+127) --
    f32x4 key[8];
    #pragma unroll
    for (int c = 0; c < 8; c++) {
        int ctl = w * 8 + c;
        int ct = slab * 128 + ctl;
        f32x4 a = (f32x4){0.f, 0.f, 0.f, 0.f};
        #pragma unroll
        for (int kk = 0; kk < 4; kk++) {
            s16x8 bh = ldfrag(xhiF + ((size_t)(ct * 4 + kk)) * 512 + lane * 8);
            s16x8 bl = ldfrag(xloF + ((size_t)(ct * 4 + kk)) * 512 + lane * 8);
            a = __builtin_amdgcn_mfma_f32_16x16x32_bf16(ahi[kk], bh, a, 0, 0, 0);
            a = __builtin_amdgcn_mfma_f32_16x16x32_bf16(alo[kk], bh, a, 0, 0, 0);
            a = __builtin_amdgcn_mfma_f32_16x16x32_bf16(ahi[kk], bl, a, 0, 0, 0);
        }
        float xxc = xx[slab * 2048 + ctl * 16 + cl];
        #pragma unroll
        for (int r = 0; r < 4; r++) a[r] = 2.0f * a[r] - xxc;
        key[c] = a;
    }

    // ---- chunk maxima: chunks of 32 cols (4 cl x 8 c), 64 chunks/row ----
    {
        float m[4];
        #pragma unroll
        for (int r = 0; r < 4; r++) {
            float mm = key[0][r];
            #pragma unroll
            for (int c = 1; c < 8; c++) mm = fmaxf(mm, key[c][r]);
            mm = fmaxf(mm, __shfl_xor(mm, 1));
            mm = fmaxf(mm, __shfl_xor(mm, 2));
            m[r] = mm;
        }
        if ((cl & 3) == 0) {
            #pragma unroll
            for (int r = 0; r < 4; r++)
                chm[quad * 4 + r][w * 4 + (cl >> 2)] = m[r];
        }
    }
    __syncthreads();

    // ---- per-row threshold: wave w sorts row w's 64 chunk maxima ----
    {
        float bs = chm[w][lane];
        #pragma unroll
        for (int k = 2; k <= 64; k <<= 1) {
            #pragma unroll
            for (int j = k >> 1; j > 0; j >>= 1) {
                float o = __shfl_xor(bs, j);
                bool dirDesc = (lane & k) != 0;
                bool upper   = (lane & j) != 0;
                bs = (upper != dirDesc) ? fmaxf(bs, o) : fminf(bs, o);
            }
        }
        float T = __shfl(bs, 44);           // 20th largest chunk max <= v20
        if (lane == 0) Trow[w] = T;
    }
    __syncthreads();

    // ---- survivor compaction (atomic append per row) ----
    #pragma unroll
    for (int r = 0; r < 4; r++) {
        int row = quad * 4 + r;
        float T = Trow[row];
        #pragma unroll
        for (int c = 0; c < 8; c++) {
            float v = key[c][r];
            if (v >= T) {
                int pos = atomicAdd(&rowcnt[row], 1);
                if (pos < 256) {
                    sv[row][pos] = v;
                    si[row][pos] = w * 128 + c * 16 + cl;
                }
            }
        }
    }
    __syncthreads();
    if (tt == 0) {
        int o = 0;
        for (int i = 0; i < 16; i++) o |= (rowcnt[i] > 256) ? 1 : 0;
        ovfAll = o;
    }
    __syncthreads();
    int ovf = ovfAll;

    // ---- selection: wave w owns row w ----
    int S = rowcnt[w];
    if (S <= 256) {
        float vl[4]; int il[4];
        #pragma unroll
        for (int s = 0; s < 4; s++) {
            int g = lane + s * 64;
            bool ok = g < S;
            vl[s] = ok ? sv[w][g] : -3.4e38f;
            il[s] = ok ? si[w][g] : 0x7FFFFFFF;
        }
        unsigned removed = 0u;
        for (int iter = 0; iter < KNN; iter++) {
            float bv = -3.4e38f; int bi = 0x7FFFFFFF;
            #pragma unroll
            for (int s = 0; s < 4; s++) {
                bool live = ((removed >> s) & 1u) == 0u;
                if (live && (vl[s] > bv || (vl[s] == bv && il[s] < bi))) {
                    bv = vl[s]; bi = il[s];
                }
            }
            MERGE(32) MERGE(16) MERGE(8) MERGE(4) MERGE(2) MERGE(1)
            if (lane == 0)
                idxbuf[(size_t)(slab * 2048 + rtl * 16 + w) * KNN + iter] = bi & 2047;
            #pragma unroll
            for (int s = 0; s < 4; s++)     // indices unique: safe removal
                if (il[s] == bi) removed |= 1u << s;
        }
    }

    // ---- exact overflow fallback (never expected; correctness only) ----
    if (ovf) {
        #pragma unroll
        for (int c = 0; c < 8; c++)
            #pragma unroll
            for (int r = 0; r < 4; r++)
                scratch[((size_t)rt * 16 + quad * 4 + r) * 2048 + w * 128 + c * 16 + cl]
                    = key[c][r];
        __syncthreads();
        if (rowcnt[w] > 256) {
            const float* rowp = scratch + ((size_t)rt * 16 + w) * 2048;
            float rv[32];
            #pragma unroll
            for (int j = 0; j < 32; j++) rv[j] = rowp[j * 64 + lane];
            unsigned removed = 0u;
            for (int iter = 0; iter < KNN; iter++) {
                float bv = -3.4e38f; int bi = 0;
                #pragma unroll
                for (int sl = 0; sl < 32; sl++) {
                    bool live = ((removed >> sl) & 1u) == 0u;
                    if (live && rv[sl] > bv) { bv = rv[sl]; bi = sl * 64 + lane; }
                }
                MERGE(32) MERGE(16) MERGE(8) MERGE(4) MERGE(2) MERGE(1)
                if (lane == 0)
                    idxbuf[(size_t)(slab * 2048 + rtl * 16 + w) * KNN + iter] = bi;
                if ((bi & 63) == lane) removed |= 1u << (bi >> 6);
            }
        }
    }
}

// ---------------------------------------------------------------------------
// k3: sparse mutual-KNN attention, 2 points/block; inline mutuality scan.
// ---------------------------------------------------------------------------
__global__ __launch_bounds__(256) void k3_attn(
    fp qT, fp kT, fp vT, const int* idxbuf, float* avT) {
    __shared__ float sbuf[2][KNN * 4];
    __shared__ int   mlist[2][KNN];
    __shared__ int   cnt_s[2];
    int tt = threadIdx.x;
    int half = tt >> 7, t = tt & 127;
    int p = blockIdx.x * 2 + half;
    int b = p >> 11, n = p & 2047;
    int bbase = b * NPT;
    int h = t >> 5;

    if ((tt >> 6) == half * 2) {
        int lane = tt & 63;
        bool fl = false; int m = 0;
        if (lane < KNN) {
            m = idxbuf[(size_t)p * KNN + lane] & 2047;
            const int4* mrow = reinterpret_cast<const int4*>(idxbuf + (size_t)(bbase + m) * KNN);
            int4 r0 = mrow[0], r1 = mrow[1], r2 = mrow[2], r3 = mrow[3], r4 = mrow[4];
            fl = (r0.x == n) || (r0.y == n) || (r0.z == n) || (r0.w == n)
              || (r1.x == n) || (r1.y == n) || (r1.z == n) || (r1.w == n)
              || (r2.x == n) || (r2.y == n) || (r2.z == n) || (r2.w == n)
              || (r3.x == n) || (r3.y == n) || (r3.z == n) || (r3.w == n)
              || (r4.x == n) || (r4.y == n) || (r4.z == n) || (r4.w == n);
        }
        unsigned long long mask = __ballot(fl);
        int pos = __popcll(mask & ((1ull << lane) - 1ull));
        if (fl) mlist[half][pos] = m;
        if (lane == 0) cnt_s[half] = (int)__popcll(mask);
    }
    __syncthreads();

    int cnt = cnt_s[half];
    float qv = qT[(size_t)p * 128 + t];
    for (int jj = 0; jj < cnt; jj++) {
        int m = mlist[half][jj];
        float prod = qv * kT[(size_t)(bbase + m) * 128 + t];
        prod += __shfl_xor(prod, 16);
        prod += __shfl_xor(prod, 8);
        prod += __shfl_xor(prod, 4);
        prod += __shfl_xor(prod, 2);
        prod += __shfl_xor(prod, 1);
        if ((t & 31) == 0) sbuf[half][jj * 4 + h] = prod * 0.17677669529663687f;
    }
    __syncthreads();

    float mx = -3.4e38f;
    for (int j = 0; j < cnt; j++) mx = fmaxf(mx, sbuf[half][j * 4 + h]);
    float den = 0.f;
    for (int j = 0; j < cnt; j++) den += expf(sbuf[half][j * 4 + h] - mx);
    float inv = (cnt > 0) ? (1.0f / den) : 0.0f;
    float acc = 0.f;
    for (int j = 0; j < cnt; j++) {
        float pw = expf(sbuf[half][j * 4 + h] - mx) * inv;
        acc += pw * vT[(size_t)(bbase + mlist[half][j]) * 128 + t];
    }
    avT[(size_t)p * 128 + t] = acc;
}

// ---------------------------------------------------------------------------
// k4b: h = w1x@x + W@av + b1p via MFMA (K=256); epilogue: hbuf + BN stats.
// ---------------------------------------------------------------------------
__global__ __launch_bounds__(256) void k4b_h(
    const ushort* xhiF, const ushort* xloF, const float* avT,
    const ushort* wcFhi, const ushort* wcFlo,
    const float* b1p, float* hbuf, float* stats) {
    int t = threadIdx.x, cs = t >> 6, lane = t & 63;
    int rt = blockIdx.x;                    // 0..255
    int p0 = rt * 16;

    f32x4 acc[4];
    #pragma unroll
    for (int j = 0; j < 4; j++) acc[j] = (f32x4){0.f, 0.f, 0.f, 0.f};

    for (int kk = 0; kk < 8; kk++) {
        s16x8 ahi, alo;
        if (kk < 4) {
            ahi = ldfrag(xhiF + ((size_t)(rt * 4 + kk)) * 512 + lane * 8);
            alo = ldfrag(xloF + ((size_t)(rt * 4 + kk)) * 512 + lane * 8);
        } else {
            const float* arow = avT + (size_t)(p0 + (lane & 15)) * 128
                              + (kk - 4) * 32 + (lane >> 4) * 8;
            f8_hilo(arow, &ahi, &alo);
        }
        #pragma unroll
        for (int j = 0; j < 4; j++) {
            int nt = cs * 4 + j;
            s16x8 bhi = ldfrag(wcFhi + ((size_t)(nt * 8 + kk)) * 512 + lane * 8);
            s16x8 blo = ldfrag(wcFlo + ((size_t)(nt * 8 + kk)) * 512 + lane * 8);
            acc[j] = __builtin_amdgcn_mfma_f32_16x16x32_bf16(ahi, bhi, acc[j], 0, 0, 0);
            acc[j] = __builtin_amdgcn_mfma_f32_16x16x32_bf16(alo, bhi, acc[j], 0, 0, 0);
            acc[j] = __builtin_amdgcn_mfma_f32_16x16x32_bf16(ahi, blo, acc[j], 0, 0, 0);
        }
    }

    int cl = lane & 15, quad = lane >> 4;
    #pragma unroll
    for (int j = 0; j < 4; j++) {
        int o = cs * 64 + j * 16 + cl;
        float bb = b1p[o];
        float s = 0.f, s2 = 0.f;
        #pragma unroll
        for (int r = 0; r < 4; r++) {
            float v = acc[j][r] + bb;
            hbuf[(size_t)(p0 + quad * 4 + r) * 256 + o] = v;
            s += v; s2 += v * v;
        }
        s  += __shfl_xor(s, 16);  s  += __shfl_xor(s, 32);
        s2 += __shfl_xor(s2, 16); s2 += __shfl_xor(s2, 32);
        if (quad == 0) {
            atomicAdd(&stats[o], s);
            atomicAdd(&stats[256 + o], s2);
        }
    }
}

// ---------------------------------------------------------------------------
// k5b: out = w2@relu(BN(h)) + b2 + x via MFMA (K=256), BN in-register.
// ---------------------------------------------------------------------------
__global__ __launch_bounds__(256) void k5b_out(
    const float* hbuf, const float* stats, fp gamma, fp beta,
    const ushort* w2Fhi, const ushort* w2Flo,
    fp b2, fp xbf, float* out) {
    int t = threadIdx.x, wvi = t >> 6, lane = t & 63;
    int rt = blockIdx.x;                    // 0..255
    int p0 = rt * 16;

    f32x4 acc[2];
    acc[0] = (f32x4){0.f, 0.f, 0.f, 0.f};
    acc[1] = (f32x4){0.f, 0.f, 0.f, 0.f};

    for (int kk = 0; kk < 8; kk++) {
        int c0 = kk * 32 + (lane >> 4) * 8;
        const float* hrow = hbuf + (size_t)(p0 + (lane & 15)) * 256 + c0;
        float4 f0 = *reinterpret_cast<const float4*>(hrow);
        float4 f1 = *reinterpret_cast<const float4*>(hrow + 4);
        float4 s0 = *reinterpret_cast<const float4*>(stats + c0);
        float4 s1 = *reinterpret_cast<const float4*>(stats + c0 + 4);
        float4 q0 = *reinterpret_cast<const float4*>(stats + 256 + c0);
        float4 q1 = *reinterpret_cast<const float4*>(stats + 256 + c0 + 4);
        float4 g0 = *reinterpret_cast<const float4*>(gamma + c0);
        float4 g1 = *reinterpret_cast<const float4*>(gamma + c0 + 4);
        float4 e0 = *reinterpret_cast<const float4*>(beta + c0);
        float4 e1 = *reinterpret_cast<const float4*>(beta + c0 + 4);
        float f[8] = {f0.x, f0.y, f0.z, f0.w, f1.x, f1.y, f1.z, f1.w};
        float sm[8] = {s0.x, s0.y, s0.z, s0.w, s1.x, s1.y, s1.z, s1.w};
        float sq[8] = {q0.x, q0.y, q0.z, q0.w, q1.x, q1.y, q1.z, q1.w};
        float gm[8] = {g0.x, g0.y, g0.z, g0.w, g1.x, g1.y, g1.z, g1.w};
        float bt[8] = {e0.x, e0.y, e0.z, e0.w, e1.x, e1.y, e1.z, e1.w};
        union { ushort u[8]; s16x8 s; } H, L;
        #pragma unroll
        for (int j = 0; j < 8; j++) {
            float mu  = sm[j] * (1.0f / 4096.0f);
            float var = fmaxf(sq[j] * (1.0f / 4096.0f) - mu * mu, 0.0f);
            float a    = gm[j] / sqrtf(var + 1e-5f);
            float cadd = bt[j] - mu * a;
            float v = fmaxf(f[j] * a + cadd, 0.0f);
            ushort hi = f2bf_rne(v);
            H.u[j] = hi;
            L.u[j] = f2bf_rne(v - bfbits2f(hi));
        }
        s16x8 ahi = H.s, alo = L.s;
        #pragma unroll
        for (int jj = 0; jj < 2; jj++) {
            int nt = wvi * 2 + jj;
            s16x8 bhi = ldfrag(w2Fhi + ((size_t)(nt * 8 + kk)) * 512 + lane * 8);
            s16x8 blo = ldfrag(w2Flo + ((size_t)(nt * 8 + kk)) * 512 + lane * 8);
            acc[jj] = __builtin_amdgcn_mfma_f32_16x16x32_bf16(ahi, bhi, acc[jj], 0, 0, 0);
            acc[jj] = __builtin_amdgcn_mfma_f32_16x16x32_bf16(alo, bhi, acc[jj], 0, 0, 0);
            acc[jj] = __builtin_amdgcn_mfma_f32_16x16x32_bf16(ahi, blo, acc[jj], 0, 0, 0);
        }
    }
    int cl = lane & 15, quad = lane >> 4;
    int b = p0 >> 11, n0 = p0 & 2047;
    #pragma unroll
    for (int jj = 0; jj < 2; jj++) {
        int o = (wvi * 2 + jj) * 16 + cl;
        float bb = b2[o];
        size_t base = (size_t)b * 128 * NPT + (size_t)o * NPT + n0 + quad * 4;
        float4 xv = *reinterpret_cast<const float4*>(xbf + base);
        float4 ov;
        ov.x = acc[jj][0] + bb + xv.x;
        ov.y = acc[jj][1] + bb + xv.y;
        ov.z = acc[jj][2] + bb + xv.z;
        ov.w = acc[jj][3] + bb + xv.w;
        *reinterpret_cast<float4*>(out + base) = ov;
    }
}

// ---------------------------------------------------------------------------
// Workspace layout (44,978,176 B; scratch only touched on topk overflow):
//   0        qT 2MB [fused->k3]  <- hbuf 4MB (k4b->k5b) aliases qT+kT
//   2097152  kT 2MB | 4194304 vT 2MB | 6291456 avT 2MB [k3->k4b]
//   8388608  xx 16KB | 8404992 idxb 320KB | 8732672 stats 2KB | 8734720 b1p 2KB
//   8736768  wq/wk/wv frags 6x32KB
//   8933376  wcFhi/lo 2x128KB | 9195520 w2Fhi/lo 2x64KB
//   9326592  xhiF 1MB | 10375168 xloF 1MB
//   11423744 scratch 32MB (topk overflow fallback only)
// ---------------------------------------------------------------------------
#define WS_FULL 44978176u

extern "C" void kernel_launch(void* const* d_in, const int* in_sizes, int n_in,
                              void* d_out, int out_size, void* d_ws, size_t ws_size,
                              hipStream_t stream) {
    fp desc1 = (fp)d_in[0];
    fp wq = (fp)d_in[1];  fp bq = (fp)d_in[2];
    fp wk = (fp)d_in[3];  fp bk = (fp)d_in[4];
    fp wv = (fp)d_in[5];  fp bv = (fp)d_in[6];
    fp wm = (fp)d_in[7];  fp bm = (fp)d_in[8];
    fp w1 = (fp)d_in[9];  fp b1 = (fp)d_in[10];
    fp gamma = (fp)d_in[11]; fp beta = (fp)d_in[12];
    fp w2 = (fp)d_in[13]; fp b2 = (fp)d_in[14];

    if (ws_size < (size_t)WS_FULL) return;  // all-zero out => ws too small

    char* ws = (char*)d_ws;
    float*  qT    = (float*) (ws + 0);
    float*  kT    = (float*) (ws + 2097152);
    float*  vT    = (float*) (ws + 4194304);
    float*  avT   = (float*) (ws + 6291456);
    float*  xx    = (float*) (ws + 8388608);
    int*    idxb  = (int*)   (ws + 8404992);
    float*  stats = (float*) (ws + 8732672);
    float*  b1p   = (float*) (ws + 8734720);
    ushort* wqFhi = (ushort*)(ws + 8736768);
    ushort* wqFlo = (ushort*)(ws + 8769536);
    ushort* wkFhi = (ushort*)(ws + 8802304);
    ushort* wkFlo = (ushort*)(ws + 8835072);
    ushort* wvFhi = (ushort*)(ws + 8867840);
    ushort* wvFlo = (ushort*)(ws + 8900608);
    ushort* wcFhi = (ushort*)(ws + 8933376);
    ushort* wcFlo = (ushort*)(ws + 9064448);
    ushort* w2Fhi = (ushort*)(ws + 9195520);
    ushort* w2Flo = (ushort*)(ws + 9261056);
    ushort* xhiF  = (ushort*)(ws + 9326592);
    ushort* xloF  = (ushort*)(ws + 10375168);
    float*  scratch = (float*)(ws + 11423744);
    float*  hbuf  = (float*) (ws + 0);      // aliases qT+kT (dead after k3)

    prep_all<<<835, 256, 0, stream>>>(desc1, wq, wk, wv, wm, w1, w2, bm, b1,
                                      xx, xhiF, xloF,
                                      wqFhi, wqFlo, wkFhi, wkFlo, wvFhi, wvFlo,
                                      wcFhi, wcFlo, w2Fhi, w2Flo, b1p, stats);
    gemm_key_topk<<<256, 1024, 0, stream>>>(xhiF, xloF, xx,
                                            wqFhi, wqFlo, wkFhi, wkFlo,
                                            wvFhi, wvFlo,
                                            bq, bk, bv, qT, kT, vT, idxb,
                                            scratch);
    k3_attn<<<2048, 256, 0, stream>>>(qT, kT, vT, idxb, avT);
    k4b_h<<<256, 256, 0, stream>>>(xhiF, xloF, avT, wcFhi, wcFlo,
                                   b1p, hbuf, stats);
    k5b_out<<<256, 256, 0, stream>>>(hbuf, stats, gamma, beta, w2Fhi, w2Flo,
                                     b2, desc1, (float*)d_out);
}